// Round 2
// baseline (15642.450 us; speedup 1.0000x reference)
//
#include <hip/hip_runtime.h>
#include <hip/hip_bf16.h>

// Problem constants
#define E_TOTAL   800000
#define NNODES    50000
#define NNF       16
#define NEF       8
#define HIDD      300
#define MSGD      128
#define NGRAPHS   64
#define NPRED     8

#define CHUNK     50000
#define NCHUNK    16   // 16 * 50000 = 800000

// ---------------------------------------------------------------------------
// Generic tiled fp32 GEMM:  C[M,N] = act(A[M,K] @ W[K,N] + bias[N])
// Block: 16x16 threads, each thread computes TM x TN = 8 x 4 outputs.
// ---------------------------------------------------------------------------
template <int BM, int BN, int BK, int TM, int TN, bool RELU>
__global__ __launch_bounds__(256) void gemm_bias_kernel(
    const float* __restrict__ A, int lda,
    const float* __restrict__ W,              // [K x N], row-major, ld = N
    const float* __restrict__ bias,           // [N]
    float* __restrict__ C, int ldc,
    int M, int N, int K)
{
    __shared__ float As[BM][BK + 1];
    __shared__ float Ws[BK][BN];

    const int tx = threadIdx.x;   // 0..15 -> N
    const int ty = threadIdx.y;   // 0..15 -> M
    const int tid = ty * 16 + tx;
    const int bm = blockIdx.y * BM;
    const int bn = blockIdx.x * BN;

    float acc[TM][TN];
#pragma unroll
    for (int i = 0; i < TM; ++i)
#pragma unroll
        for (int j = 0; j < TN; ++j) acc[i][j] = 0.f;

    for (int k0 = 0; k0 < K; k0 += BK) {
        // Load A tile (BM x BK)
#pragma unroll
        for (int p = tid; p < BM * BK; p += 256) {
            int m = p / BK, k = p % BK;
            int gm = bm + m, gk = k0 + k;
            As[m][k] = (gm < M && gk < K) ? A[(long)gm * lda + gk] : 0.f;
        }
        // Load W tile (BK x BN)
#pragma unroll
        for (int p = tid; p < BK * BN; p += 256) {
            int k = p / BN, n = p % BN;
            int gk = k0 + k, gn = bn + n;
            Ws[k][n] = (gk < K && gn < N) ? W[(long)gk * N + gn] : 0.f;
        }
        __syncthreads();

#pragma unroll
        for (int k = 0; k < BK; ++k) {
            float a[TM], w[TN];
#pragma unroll
            for (int i = 0; i < TM; ++i) a[i] = As[ty * TM + i][k];
#pragma unroll
            for (int j = 0; j < TN; ++j) w[j] = Ws[k][tx * TN + j];
#pragma unroll
            for (int i = 0; i < TM; ++i)
#pragma unroll
                for (int j = 0; j < TN; ++j)
                    acc[i][j] = fmaf(a[i], w[j], acc[i][j]);
        }
        __syncthreads();
    }

#pragma unroll
    for (int j = 0; j < TN; ++j) {
        int gn = bn + tx * TN + j;
        if (gn >= N) continue;
        float b = bias[gn];
#pragma unroll
        for (int i = 0; i < TM; ++i) {
            int gm = bm + ty * TM + i;
            if (gm >= M) continue;
            float v = acc[i][j] + b;
            if (RELU) v = fmaxf(v, 0.f);
            C[(long)gm * ldc + gn] = v;
        }
    }
}

// ---------------------------------------------------------------------------
// Build tmp = concat(x[dst], x[src], edge_attr) for a chunk of edges.
// edge_index layout: ei[0:E] = src, ei[E:2E] = dst.
// ---------------------------------------------------------------------------
__global__ void build_tmp_kernel(const float* __restrict__ x,
                                 const int* __restrict__ ei,
                                 const float* __restrict__ ea,
                                 float* __restrict__ tmp, int e0, int ne)
{
    const int F = 2 * NNF + NEF;  // 40
    int t = blockIdx.x * blockDim.x + threadIdx.x;
    if (t >= ne * F) return;
    int e = t / F, f = t % F;
    int ge = e0 + e;
    float v;
    if (f < NNF) {
        int dst = ei[E_TOTAL + ge];
        v = x[dst * NNF + f];
    } else if (f < 2 * NNF) {
        int src = ei[ge];
        v = x[src * NNF + (f - NNF)];
    } else {
        v = ea[(long)ge * NEF + (f - 2 * NNF)];
    }
    tmp[(long)e * F + f] = v;
}

// ---------------------------------------------------------------------------
// Scatter-add messages into aggr[dst].
// ---------------------------------------------------------------------------
__global__ void scatter_add_kernel(const float* __restrict__ msg,
                                   const int* __restrict__ ei,
                                   float* __restrict__ aggr, int e0, int ne)
{
    int t = blockIdx.x * blockDim.x + threadIdx.x;
    if (t >= ne * MSGD) return;
    int e = t / MSGD, c = t % MSGD;
    int dst = ei[E_TOTAL + e0 + e];
    atomicAdd(&aggr[(long)dst * MSGD + c], msg[(long)e * MSGD + c]);
}

// ---------------------------------------------------------------------------
// Graph segment boundaries (batch is sorted). starts[g] = lower_bound(batch,g)
// ---------------------------------------------------------------------------
__global__ void graph_starts_kernel(const int* __restrict__ batch,
                                    int* __restrict__ starts)
{
    int g = threadIdx.x;
    if (g > NGRAPHS) return;
    int lo = 0, hi = NNODES;
    while (lo < hi) {
        int mid = (lo + hi) >> 1;
        if (batch[mid] < g) lo = mid + 1; else hi = mid;
    }
    starts[g] = lo;
}

// ---------------------------------------------------------------------------
// Per-graph mean pool: pooled[g, f] = mean over nodes of node[i, f]
// ---------------------------------------------------------------------------
__global__ void pool_kernel(const float* __restrict__ node,
                            const int* __restrict__ starts,
                            float* __restrict__ pooled)
{
    int g = blockIdx.x;
    int f = threadIdx.x;           // blockDim = 320, features 0..299
    if (f >= HIDD) return;
    int s = starts[g], e = starts[g + 1];
    float sum = 0.f;
    for (int i = s; i < e; ++i) sum += node[(long)i * HIDD + f];
    float cnt = (float)(e - s);
    pooled[g * HIDD + f] = sum / fmaxf(cnt, 1.0f);
}

// ---------------------------------------------------------------------------
// Final linear: out[g, p] = pooled[g, :] @ lw[:, p] + lb[p]
// ---------------------------------------------------------------------------
__global__ void final_kernel(const float* __restrict__ pooled,
                             const float* __restrict__ lw,
                             const float* __restrict__ lb,
                             float* __restrict__ out)
{
    int t = threadIdx.x;           // 512 = 64 * 8
    int g = t / NPRED, p = t % NPRED;
    float s = lb[p];
    for (int k = 0; k < HIDD; ++k)
        s = fmaf(pooled[g * HIDD + k], lw[k * NPRED + p], s);
    out[g * NPRED + p] = s;
}

// ---------------------------------------------------------------------------
extern "C" void kernel_launch(void* const* d_in, const int* in_sizes, int n_in,
                              void* d_out, int out_size, void* d_ws, size_t ws_size,
                              hipStream_t stream)
{
    const float* x     = (const float*)d_in[0];
    const int*   ei    = (const int*)d_in[1];
    const float* ea    = (const float*)d_in[2];
    const int*   batch = (const int*)d_in[3];
    const float* mw1 = (const float*)d_in[4];  const float* mb1 = (const float*)d_in[5];
    const float* mw2 = (const float*)d_in[6];  const float* mb2 = (const float*)d_in[7];
    const float* mw3 = (const float*)d_in[8];  const float* mb3 = (const float*)d_in[9];
    const float* mw4 = (const float*)d_in[10]; const float* mb4 = (const float*)d_in[11];
    const float* nw1 = (const float*)d_in[12]; const float* nb1 = (const float*)d_in[13];
    const float* nw2 = (const float*)d_in[14]; const float* nb2 = (const float*)d_in[15];
    const float* nw3 = (const float*)d_in[16]; const float* nb3 = (const float*)d_in[17];
    const float* nw4 = (const float*)d_in[18]; const float* nb4 = (const float*)d_in[19];
    const float* lw  = (const float*)d_in[20]; const float* lb  = (const float*)d_in[21];
    float* out = (float*)d_out;

    // Workspace layout (all 256B aligned). ~154 MB total.
    char* ws = (char*)d_ws;
    size_t off = 0;
    auto alloc = [&](size_t bytes) -> void* {
        void* p = ws + off;
        off += (bytes + 255) & ~(size_t)255;
        return p;
    };
    float* tmp    = (float*)alloc((size_t)CHUNK * 40 * sizeof(float));     // 8 MB
    float* hA     = (float*)alloc((size_t)CHUNK * HIDD * sizeof(float));   // 60 MB
    float* hB     = (float*)alloc((size_t)CHUNK * HIDD * sizeof(float));   // 60 MB
    float* aggr   = (float*)alloc((size_t)NNODES * MSGD * sizeof(float));  // 25.6 MB
    float* pooled = (float*)alloc((size_t)NGRAPHS * HIDD * sizeof(float));
    int*   starts = (int*)alloc((NGRAPHS + 1) * sizeof(int));
    // Node MLP reuses hA/hB (CHUNK == NNODES).
    float* nodeA = hA;
    float* nodeB = hB;

    hipMemsetAsync(aggr, 0, (size_t)NNODES * MSGD * sizeof(float), stream);
    graph_starts_kernel<<<1, 128, 0, stream>>>(batch, starts);

    dim3 blk(16, 16);
    const int gy_edge = (CHUNK + 127) / 128;   // 391
    const int gx_hid  = (HIDD + 63) / 64;      // 5
    const int gx_msg  = (MSGD + 63) / 64;      // 2

    for (int c = 0; c < NCHUNK; ++c) {
        int e0 = c * CHUNK;
        build_tmp_kernel<<<(CHUNK * 40 + 255) / 256, 256, 0, stream>>>(x, ei, ea, tmp, e0, CHUNK);
        gemm_bias_kernel<128, 64, 16, 8, 4, true><<<dim3(gx_hid, gy_edge), blk, 0, stream>>>(
            tmp, 40, mw1, mb1, hA, HIDD, CHUNK, HIDD, 40);
        gemm_bias_kernel<128, 64, 16, 8, 4, true><<<dim3(gx_hid, gy_edge), blk, 0, stream>>>(
            hA, HIDD, mw2, mb2, hB, HIDD, CHUNK, HIDD, HIDD);
        gemm_bias_kernel<128, 64, 16, 8, 4, true><<<dim3(gx_hid, gy_edge), blk, 0, stream>>>(
            hB, HIDD, mw3, mb3, hA, HIDD, CHUNK, HIDD, HIDD);
        gemm_bias_kernel<128, 64, 16, 8, 4, false><<<dim3(gx_msg, gy_edge), blk, 0, stream>>>(
            hA, HIDD, mw4, mb4, hB, MSGD, CHUNK, MSGD, HIDD);
        scatter_add_kernel<<<(CHUNK * MSGD + 255) / 256, 256, 0, stream>>>(hB, ei, aggr, e0, CHUNK);
    }

    // Node MLP
    const int gy_node = (NNODES + 127) / 128;  // 391
    gemm_bias_kernel<128, 64, 16, 8, 4, true><<<dim3(gx_hid, gy_node), blk, 0, stream>>>(
        aggr, MSGD, nw1, nb1, nodeA, HIDD, NNODES, HIDD, MSGD);
    gemm_bias_kernel<128, 64, 16, 8, 4, true><<<dim3(gx_hid, gy_node), blk, 0, stream>>>(
        nodeA, HIDD, nw2, nb2, nodeB, HIDD, NNODES, HIDD, HIDD);
    gemm_bias_kernel<128, 64, 16, 8, 4, true><<<dim3(gx_hid, gy_node), blk, 0, stream>>>(
        nodeB, HIDD, nw3, nb3, nodeA, HIDD, NNODES, HIDD, HIDD);
    gemm_bias_kernel<128, 64, 16, 8, 4, false><<<dim3(gx_hid, gy_node), blk, 0, stream>>>(
        nodeA, HIDD, nw4, nb4, nodeB, HIDD, NNODES, HIDD, HIDD);

    pool_kernel<<<NGRAPHS, 320, 0, stream>>>(nodeB, starts, pooled);
    final_kernel<<<1, 512, 0, stream>>>(pooled, lw, lb, out);
}

// Round 3
// 2329.174 us; speedup vs baseline: 6.7159x; 6.7159x over previous
//
#include <hip/hip_runtime.h>
#include <hip/hip_bf16.h>
#include <stdint.h>

// Problem constants
#define E_TOTAL   800000
#define NNODES    50000
#define NNF       16
#define NEF       8
#define NGRAPHS   64
#define NPRED     8

#define CHUNK     50000
#define NCHUNK    16          // 16 * 50000 = 800000
#define MPAD      50048       // 391 * 128  (rows padded to tile)

typedef short v8s __attribute__((ext_vector_type(8)));
typedef float v4f __attribute__((ext_vector_type(4)));

// ---------------------------------------------------------------------------
// global -> LDS direct copy, 16B per lane. LDS dest = wave-uniform base +
// lane*16 (hardware behavior). Global source is per-lane.
// ---------------------------------------------------------------------------
__device__ __forceinline__ void gload_lds16(const void* g, void* l) {
    __builtin_amdgcn_global_load_lds(
        (const __attribute__((address_space(1))) uint32_t*)g,
        (__attribute__((address_space(3))) uint32_t*)l,
        16, 0, 0);
}

// ---------------------------------------------------------------------------
// bf16 MFMA GEMM:  C[M,N] = act(A @ W + bias)
//   A  : bf16 [Mpad][Kpad] row-major (Mpad = gridDim.y*128, Kpad % 64 == 0)
//   Wt : bf16 [Npad][Kpad] (W transposed; Npad = gridDim.x*64)
//   bias: fp32 [Npad]
// Tile: 128x64, BK=64, 256 threads = 4 waves in 2x2; wave tile 64x32 =
// 4x2 fragments of 16x16, mfma_f32_16x16x32_bf16.
// LDS tiles stored linearly (global_load_lds), with the 16B chunk index
// XOR-swizzled against (row&7) applied on the GLOBAL source address, so the
// strided ds_read_b128 fragment reads are conflict-free (2-way only).
// ---------------------------------------------------------------------------
template <bool RELU, bool OUTBF16>
__global__ __launch_bounds__(256)
void mfma_gemm(const __hip_bfloat16* __restrict__ A,
               const __hip_bfloat16* __restrict__ Wt,
               const float* __restrict__ bias,
               void* __restrict__ Cv,
               int Kpad, int ldc)
{
    __shared__ __align__(16) char smem[24576];
    char* AsC = smem;           // 128 x 64 bf16 = 16384 B (row stride 128 B)
    char* WsC = smem + 16384;   //  64 x 64 bf16 =  8192 B

    const int tid  = threadIdx.x;
    const int lane = tid & 63;
    const int wave = tid >> 6;
    const int wrow = wave >> 1;   // 0..1
    const int wcol = wave & 1;    // 0..1

    const size_t KpadB = (size_t)Kpad * 2;
    const char* Ag = (const char*)(A  + (size_t)blockIdx.y * 128 * Kpad);
    const char* Wg = (const char*)(Wt + (size_t)blockIdx.x * 64  * Kpad);

    const int rsub = lane >> 3;   // 0..7 (row within 8-row segment)
    const int csub = lane & 7;    // 0..7 (16B chunk within 128B row)

    v4f acc[4][2];
#pragma unroll
    for (int i = 0; i < 4; ++i)
#pragma unroll
        for (int j = 0; j < 2; ++j) acc[i][j] = (v4f){0.f, 0.f, 0.f, 0.f};

    const int nk = Kpad >> 6;
    for (int kt = 0; kt < nk; ++kt) {
        const size_t k0B = (size_t)kt * 128;   // 64 bf16 = 128 bytes
        // Stage A tile: 16 segments of 1KB; wave w takes segs w, w+4, w+8, w+12
#pragma unroll
        for (int q = 0; q < 4; ++q) {
            int seg = q * 4 + wave;
            int row = seg * 8 + rsub;                  // 0..127
            int sc  = csub ^ (row & 7);                // pre-swizzled source chunk
            gload_lds16(Ag + (size_t)row * KpadB + k0B + sc * 16,
                        AsC + seg * 1024);
        }
        // Stage W tile: 8 segments of 1KB
#pragma unroll
        for (int q = 0; q < 2; ++q) {
            int seg = q * 4 + wave;
            int row = seg * 8 + rsub;                  // 0..63 (= output col)
            int sc  = csub ^ (row & 7);
            gload_lds16(Wg + (size_t)row * KpadB + k0B + sc * 16,
                        WsC + seg * 1024);
        }
        asm volatile("s_waitcnt vmcnt(0)" ::: "memory");
        __syncthreads();

#pragma unroll
        for (int kb = 0; kb < 2; ++kb) {
            v8s a[4], b[2];
#pragma unroll
            for (int fi = 0; fi < 4; ++fi) {
                int r = wrow * 64 + fi * 16 + (lane & 15);
                int c = kb * 4 + (lane >> 4);
                a[fi] = *(const v8s*)(AsC + r * 128 + ((c ^ (r & 7)) * 16));
            }
#pragma unroll
            for (int fj = 0; fj < 2; ++fj) {
                int r = wcol * 32 + fj * 16 + (lane & 15);
                int c = kb * 4 + (lane >> 4);
                b[fj] = *(const v8s*)(WsC + r * 128 + ((c ^ (r & 7)) * 16));
            }
#pragma unroll
            for (int fi = 0; fi < 4; ++fi)
#pragma unroll
                for (int fj = 0; fj < 2; ++fj)
                    acc[fi][fj] = __builtin_amdgcn_mfma_f32_16x16x32_bf16(
                        a[fi], b[fj], acc[fi][fj], 0, 0, 0);
        }
        __syncthreads();
    }

    // Epilogue. C/D layout: col = lane&15, row = (lane>>4)*4 + r  [m89/m91]
    const int rowbase = blockIdx.y * 128 + wrow * 64;
    const int colbase = blockIdx.x * 64 + wcol * 32;
#pragma unroll
    for (int fj = 0; fj < 2; ++fj) {
        int col = colbase + fj * 16 + (lane & 15);
        float bb = bias[col];
#pragma unroll
        for (int fi = 0; fi < 4; ++fi) {
#pragma unroll
            for (int r = 0; r < 4; ++r) {
                int row = rowbase + fi * 16 + (lane >> 4) * 4 + r;
                float v = acc[fi][fj][r] + bb;
                if (RELU) v = fmaxf(v, 0.f);
                if (OUTBF16)
                    ((__hip_bfloat16*)Cv)[(size_t)row * ldc + col] = __float2bfloat16(v);
                else
                    ((float*)Cv)[(size_t)row * ldc + col] = v;
            }
        }
    }
}

// ---------------------------------------------------------------------------
// Repack fp32 weight [K][N] row-major -> bf16 transposed padded [Npad][Kpad]
// ---------------------------------------------------------------------------
__global__ void repack_w(const float* __restrict__ src, __hip_bfloat16* __restrict__ dst,
                         int K, int N, int Kpad, int Npad)
{
    int t = blockIdx.x * 256 + threadIdx.x;
    if (t >= Kpad * Npad) return;
    int n = t / Kpad, k = t % Kpad;
    float v = (k < K && n < N) ? src[(size_t)k * N + n] : 0.f;
    dst[(size_t)n * Kpad + k] = __float2bfloat16(v);
}

__global__ void pad_bias(const float* __restrict__ src, float* __restrict__ dst,
                         int N, int Npad)
{
    int t = blockIdx.x * 256 + threadIdx.x;
    if (t < Npad) dst[t] = (t < N) ? src[t] : 0.f;
}

// ---------------------------------------------------------------------------
// tmp(bf16, [MPAD][64]) = [x[dst] | x[src] | edge_attr | 0-pad] for a chunk.
// ei[0:E] = src, ei[E:2E] = dst.
// ---------------------------------------------------------------------------
__global__ void build_tmp_bf16(const float* __restrict__ x,
                               const int* __restrict__ ei,
                               const float* __restrict__ ea,
                               __hip_bfloat16* __restrict__ tmp, int e0)
{
    int t = blockIdx.x * 256 + threadIdx.x;   // CHUNK*64 threads
    int e = t >> 6, f = t & 63;
    if (e >= CHUNK) return;
    int ge = e0 + e;
    float v = 0.f;
    if (f < NNF) {
        int dst = ei[E_TOTAL + ge];
        v = x[dst * NNF + f];
    } else if (f < 2 * NNF) {
        int src = ei[ge];
        v = x[src * NNF + (f - NNF)];
    } else if (f < 2 * NNF + NEF) {
        v = ea[(size_t)ge * NEF + (f - 2 * NNF)];
    }
    tmp[(size_t)e * 64 + f] = __float2bfloat16(v);
}

// ---------------------------------------------------------------------------
// Scatter-add fp32 messages into aggr[dst]  (msg ld = 128)
// ---------------------------------------------------------------------------
__global__ void scatter_add_kernel(const float* __restrict__ msg,
                                   const int* __restrict__ ei,
                                   float* __restrict__ aggr, int e0)
{
    int t = blockIdx.x * 256 + threadIdx.x;
    if (t >= CHUNK * 128) return;
    int e = t >> 7, c = t & 127;
    int dst = ei[E_TOTAL + e0 + e];
    atomicAdd(&aggr[(size_t)dst * 128 + c], msg[(size_t)e * 128 + c]);
}

// ---------------------------------------------------------------------------
// aggr fp32 [MPAD][128] -> bf16 (rows >= NNODES forced to 0)
// ---------------------------------------------------------------------------
__global__ void cvt_aggr(const float* __restrict__ aggr, __hip_bfloat16* __restrict__ out)
{
    int t = blockIdx.x * 256 + threadIdx.x;   // MPAD*128 threads
    int row = t >> 7;
    float v = (row < NNODES) ? aggr[t] : 0.f;
    out[t] = __float2bfloat16(v);
}

// ---------------------------------------------------------------------------
__global__ void graph_starts_kernel(const int* __restrict__ batch,
                                    int* __restrict__ starts)
{
    int g = threadIdx.x;
    if (g > NGRAPHS) return;
    int lo = 0, hi = NNODES;
    while (lo < hi) {
        int mid = (lo + hi) >> 1;
        if (batch[mid] < g) lo = mid + 1; else hi = mid;
    }
    starts[g] = lo;
}

// ---------------------------------------------------------------------------
// Mean pool: node fp32 [MPAD][320] (valid cols 0..299) -> pooled [64][300]
// grid (64, 10); block 256 = 32 cols x 8 row-lanes
// ---------------------------------------------------------------------------
__global__ void pool_kernel(const float* __restrict__ node,
                            const int* __restrict__ starts,
                            float* __restrict__ pooled)
{
    __shared__ float red[8][32];
    int g   = blockIdx.x;
    int col = blockIdx.y * 32 + (threadIdx.x & 31);
    int rl  = threadIdx.x >> 5;   // 0..7
    int s = starts[g], e = starts[g + 1];
    float sum = 0.f;
    if (col < 300)
        for (int i = s + rl; i < e; i += 8) sum += node[(size_t)i * 320 + col];
    red[rl][threadIdx.x & 31] = sum;
    __syncthreads();
    if (rl == 0 && col < 300) {
        float tot = 0.f;
#pragma unroll
        for (int r = 0; r < 8; ++r) tot += red[r][threadIdx.x & 31];
        float cnt = (float)(e - s);
        pooled[g * 300 + col] = tot / fmaxf(cnt, 1.0f);
    }
}

// ---------------------------------------------------------------------------
__global__ void final_kernel(const float* __restrict__ pooled,
                             const float* __restrict__ lw,
                             const float* __restrict__ lb,
                             float* __restrict__ out)
{
    int t = threadIdx.x;          // 512 = 64 * 8
    int g = t / NPRED, p = t % NPRED;
    float s = lb[p];
    for (int k = 0; k < 300; ++k)
        s = fmaf(pooled[g * 300 + k], lw[k * NPRED + p], s);
    out[g * NPRED + p] = s;
}

// ---------------------------------------------------------------------------
extern "C" void kernel_launch(void* const* d_in, const int* in_sizes, int n_in,
                              void* d_out, int out_size, void* d_ws, size_t ws_size,
                              hipStream_t stream)
{
    const float* x     = (const float*)d_in[0];
    const int*   ei    = (const int*)d_in[1];
    const float* ea    = (const float*)d_in[2];
    const int*   batch = (const int*)d_in[3];
    const float* mw[4] = {(const float*)d_in[4], (const float*)d_in[6],
                          (const float*)d_in[8], (const float*)d_in[10]};
    const float* mb[4] = {(const float*)d_in[5], (const float*)d_in[7],
                          (const float*)d_in[9], (const float*)d_in[11]};
    const float* nw[4] = {(const float*)d_in[12], (const float*)d_in[14],
                          (const float*)d_in[16], (const float*)d_in[18]};
    const float* nb[4] = {(const float*)d_in[13], (const float*)d_in[15],
                          (const float*)d_in[17], (const float*)d_in[19]};
    const float* lw = (const float*)d_in[20];
    const float* lb = (const float*)d_in[21];
    float* out = (float*)d_out;

    char* ws = (char*)d_ws;
    size_t off = 0;
    auto alloc = [&](size_t bytes) -> void* {
        void* p = ws + off;
        off += (bytes + 255) & ~(size_t)255;
        return p;
    };

    // Persistent activations
    __hip_bfloat16* hA = (__hip_bfloat16*)alloc((size_t)MPAD * 320 * 2);  // 32.0 MB
    __hip_bfloat16* hB = (__hip_bfloat16*)alloc((size_t)MPAD * 320 * 2);  // 32.0 MB
    // Union region U: edge-phase {aggr, aggrb, tmp, msg}; node output overlays it
    char* U = (char*)alloc((size_t)70467584);                             // 70.5 MB
    float*          aggr  = (float*)(U);                                  // 25.6 MB
    __hip_bfloat16* aggrb = (__hip_bfloat16*)(U + 25624576);              // 12.8 MB
    __hip_bfloat16* tmp   = (__hip_bfloat16*)(U + 38436864);              //  6.4 MB
    float*          msg   = (float*)(U + 44843008);                       // 25.6 MB
    float*          node  = (float*)(U);  // 64.1 MB, overlays U (edge-phase bufs dead)

    // Weights (bf16, transposed, padded) + biases (fp32, padded)
    __hip_bfloat16* mwt[4]; __hip_bfloat16* nwt[4];
    float* mbp[4]; float* nbp[4];
    const int mK[4]  = {40, 300, 300, 300}, mN[4]  = {300, 300, 300, 128};
    const int mKp[4] = {64, 320, 320, 320}, mNp[4] = {320, 320, 320, 128};
    const int nK[4]  = {128, 300, 300, 300}, nN[4] = {300, 300, 300, 300};
    const int nKp[4] = {128, 320, 320, 320}, nNp[4] = {320, 320, 320, 320};
    for (int i = 0; i < 4; ++i) {
        mwt[i] = (__hip_bfloat16*)alloc((size_t)mNp[i] * mKp[i] * 2);
        nwt[i] = (__hip_bfloat16*)alloc((size_t)nNp[i] * nKp[i] * 2);
        mbp[i] = (float*)alloc(320 * 4);
        nbp[i] = (float*)alloc(320 * 4);
    }
    float* pooled = (float*)alloc(64 * 300 * 4);
    int*   starts = (int*)alloc(65 * 4);

    // ---- weight repack + bias pad + setup ----
    for (int i = 0; i < 4; ++i) {
        repack_w<<<(mKp[i] * mNp[i] + 255) / 256, 256, 0, stream>>>(
            mw[i], mwt[i], mK[i], mN[i], mKp[i], mNp[i]);
        repack_w<<<(nKp[i] * nNp[i] + 255) / 256, 256, 0, stream>>>(
            nw[i], nwt[i], nK[i], nN[i], nKp[i], nNp[i]);
        pad_bias<<<2, 256, 0, stream>>>(mb[i], mbp[i], mN[i], mNp[i]);
        pad_bias<<<2, 256, 0, stream>>>(nb[i], nbp[i], nN[i], nNp[i]);
    }
    hipMemsetAsync(aggr, 0, (size_t)MPAD * 128 * 4, stream);
    graph_starts_kernel<<<1, 128, 0, stream>>>(batch, starts);

    const dim3 gHID(5, MPAD / 128);   // N=320
    const dim3 gMSG(2, MPAD / 128);   // N=128

    // ---- edge phase: message MLP + scatter, 16 chunks ----
    for (int c = 0; c < NCHUNK; ++c) {
        int e0 = c * CHUNK;
        build_tmp_bf16<<<(CHUNK * 64 + 255) / 256, 256, 0, stream>>>(x, ei, ea, tmp, e0);
        mfma_gemm<true,  true ><<<gHID, 256, 0, stream>>>(tmp, mwt[0], mbp[0], hA, 64, 320);
        mfma_gemm<true,  true ><<<gHID, 256, 0, stream>>>(hA,  mwt[1], mbp[1], hB, 320, 320);
        mfma_gemm<true,  true ><<<gHID, 256, 0, stream>>>(hB,  mwt[2], mbp[2], hA, 320, 320);
        mfma_gemm<false, false><<<gMSG, 256, 0, stream>>>(hA,  mwt[3], mbp[3], msg, 320, 128);
        scatter_add_kernel<<<(CHUNK * 128 + 255) / 256, 256, 0, stream>>>(msg, ei, aggr, e0);
    }

    // ---- node phase ----
    cvt_aggr<<<(MPAD * 128 + 255) / 256, 256, 0, stream>>>(aggr, aggrb);
    mfma_gemm<true,  true ><<<gHID, 256, 0, stream>>>(aggrb, nwt[0], nbp[0], hA, 128, 320);
    mfma_gemm<true,  true ><<<gHID, 256, 0, stream>>>(hA,    nwt[1], nbp[1], hB, 320, 320);
    mfma_gemm<true,  true ><<<gHID, 256, 0, stream>>>(hB,    nwt[2], nbp[2], hA, 320, 320);
    mfma_gemm<false, false><<<gHID, 256, 0, stream>>>(hA,    nwt[3], nbp[3], node, 320, 320);

    pool_kernel<<<dim3(64, 10), 256, 0, stream>>>(node, starts, pooled);
    final_kernel<<<1, 512, 0, stream>>>(pooled, lw, lb, out);
}